// Round 2
// baseline (2750.984 us; speedup 1.0000x reference)
//
#include <hip/hip_runtime.h>
#include <hip/hip_bf16.h>
#include <stdint.h>

#define NN 40000     // nodes
#define EE 150000    // edges (before self loops)
#define ET 190000    // EE + NN
#define GG 128       // graphs
#define VV 20000     // vocab
#define DD 512       // dim

// ---------------- embedding gather: x[n] = emb[node_ids[n]] ----------------
__global__ __launch_bounds__(256) void k_gather_emb(const int* __restrict__ ids,
                                                    const float4* __restrict__ emb4,
                                                    float4* __restrict__ x4) {
    int t = blockIdx.x * 256 + threadIdx.x;        // one float4 = 4 fp32; 128 per row
    int n = t >> 7, c = t & 127;
    if (n >= NN) return;
    int id = ids[n];
    x4[n * 128 + c] = emb4[id * 128 + c];
}

// ---------------- fp32 GEMM: C = A @ B  (M x K @ K x N) --------------------
// BM=BN=64, BK=16, 256 threads, 4x4 micro-tile
__global__ __launch_bounds__(256) void k_gemm(const float* __restrict__ A,
                                              const float* __restrict__ B,
                                              float* __restrict__ C,
                                              int M, int Ncols, int K) {
    __shared__ float As[16][65];   // [k][m]
    __shared__ float Bs[16][65];   // [k][n]
    int tx = threadIdx.x & 15, ty = threadIdx.x >> 4;
    int m0 = blockIdx.x * 64, n0 = blockIdx.y * 64;
    float acc[4][4] = {};
    for (int k0 = 0; k0 < K; k0 += 16) {
        for (int t = threadIdx.x; t < 1024; t += 256) {
            int ra = t >> 4, ca = t & 15;                     // A tile 64x16
            As[ca][ra] = A[(size_t)(m0 + ra) * K + k0 + ca];
            int rb = t >> 6, cb = t & 63;                     // B tile 16x64
            Bs[rb][cb] = B[(size_t)(k0 + rb) * Ncols + n0 + cb];
        }
        __syncthreads();
        #pragma unroll
        for (int kk = 0; kk < 16; ++kk) {
            float a[4], b[4];
            #pragma unroll
            for (int i = 0; i < 4; i++) a[i] = As[kk][ty * 4 + i];
            #pragma unroll
            for (int j = 0; j < 4; j++) b[j] = Bs[kk][tx * 4 + j];
            #pragma unroll
            for (int i = 0; i < 4; i++)
                #pragma unroll
                for (int j = 0; j < 4; j++) acc[i][j] += a[i] * b[j];
        }
        __syncthreads();
    }
    #pragma unroll
    for (int i = 0; i < 4; i++)
        #pragma unroll
        for (int j = 0; j < 4; j++)
            C[(size_t)(m0 + ty * 4 + i) * Ncols + n0 + tx * 4 + j] = acc[i][j];
}

// ---------------- attention scores es/ed per (node, head) -----------------
template <int H, int C>
__global__ __launch_bounds__(256) void k_attn_scores(const float* __restrict__ h,
                                                     const float* __restrict__ a_s,
                                                     const float* __restrict__ a_d,
                                                     float* __restrict__ es,
                                                     float* __restrict__ ed) {
    int wave = threadIdx.x >> 6, lane = threadIdx.x & 63;
    int gw = blockIdx.x * 4 + wave;
    if (gw >= NN * H) return;
    int node = gw / H, head = gw % H;
    const float* hrow = h + (size_t)node * (H * C) + head * C;
    float ss = 0.f, sd = 0.f;
    for (int c = lane; c < C; c += 64) {
        float hv = hrow[c];
        ss += hv * a_s[head * C + c];
        sd += hv * a_d[head * C + c];
    }
    #pragma unroll
    for (int off = 32; off; off >>= 1) {
        ss += __shfl_xor(ss, off, 64);
        sd += __shfl_xor(sd, off, 64);
    }
    if (lane == 0) { es[node * H + head] = ss; ed[node * H + head] = sd; }
}

// ---------------- CSR build ------------------------------------------------
__global__ __launch_bounds__(256) void k_count_deg(const int* __restrict__ edst,
                                                   int* __restrict__ deg) {
    int e = blockIdx.x * 256 + threadIdx.x;
    if (e >= ET) return;
    int dst = (e < EE) ? edst[e] : (e - EE);
    atomicAdd(&deg[dst], 1);
}

__global__ __launch_bounds__(1024) void k_scan(const int* __restrict__ deg,
                                               int* __restrict__ offsets) {
    __shared__ int buf[1024];
    __shared__ int carry;
    if (threadIdx.x == 0) carry = 0;
    __syncthreads();
    for (int base = 0; base < NN; base += 1024) {
        int i = base + (int)threadIdx.x;
        int v = (i < NN) ? deg[i] : 0;
        buf[threadIdx.x] = v;
        __syncthreads();
        for (int off = 1; off < 1024; off <<= 1) {
            int t = (threadIdx.x >= (unsigned)off) ? buf[threadIdx.x - off] : 0;
            __syncthreads();
            buf[threadIdx.x] += t;
            __syncthreads();
        }
        if (i < NN) offsets[i] = carry + buf[threadIdx.x] - v;   // exclusive
        __syncthreads();
        if (threadIdx.x == 1023) carry += buf[1023];
        __syncthreads();
    }
    if (threadIdx.x == 0) offsets[NN] = carry;
}

__global__ __launch_bounds__(256) void k_fill_csr(const int* __restrict__ esrc,
                                                  const int* __restrict__ edst,
                                                  const int* __restrict__ offsets,
                                                  int* __restrict__ cursor,
                                                  int* __restrict__ csr_src) {
    int e = blockIdx.x * 256 + threadIdx.x;
    if (e >= ET) return;
    int dst, src;
    if (e < EE) { dst = edst[e]; src = esrc[e]; }
    else        { dst = e - EE;  src = e - EE; }
    int slot = offsets[dst] + atomicAdd(&cursor[dst], 1);
    csr_src[slot] = src;
}

// ---------------- GAT softmax + aggregate + epilogue (per dst node) --------
template <int H, int C, bool RES>
__global__ __launch_bounds__(256) void k_gat_aggregate(const float* __restrict__ h,
                                                       const float* __restrict__ es,
                                                       const float* __restrict__ ed,
                                                       const int* __restrict__ offsets,
                                                       const int* __restrict__ csr_src,
                                                       const float* __restrict__ bias,
                                                       float* __restrict__ x) {
    constexpr int HC = H * C;
    __shared__ int   s_src[256];
    __shared__ float s_a[256 * H];
    int node = blockIdx.x;
    int beg = offsets[node];
    int deg = offsets[node + 1] - beg;
    if (deg > 256) deg = 256;   // never hit with this input (max in-deg ~ 20)
    int tid = threadIdx.x;

    if (tid < 64) {             // wave 0: per-head softmax, alpha -> LDS
        int lane = tid;
        float edl[H], m[H], sum[H];
        #pragma unroll
        for (int hh = 0; hh < H; hh++) { edl[hh] = ed[node * H + hh]; m[hh] = -1e30f; sum[hh] = 0.f; }
        for (int i = lane; i < deg; i += 64) {
            int src = csr_src[beg + i];
            s_src[i] = src;
            #pragma unroll
            for (int hh = 0; hh < H; hh++) {
                float e = es[src * H + hh] + edl[hh];
                e = e > 0.f ? e : 0.2f * e;     // leaky_relu 0.2
                s_a[i * H + hh] = e;
                m[hh] = fmaxf(m[hh], e);
            }
        }
        #pragma unroll
        for (int off = 32; off; off >>= 1)
            #pragma unroll
            for (int hh = 0; hh < H; hh++) m[hh] = fmaxf(m[hh], __shfl_xor(m[hh], off, 64));
        for (int i = lane; i < deg; i += 64) {
            #pragma unroll
            for (int hh = 0; hh < H; hh++) {
                float p = __expf(s_a[i * H + hh] - m[hh]);
                s_a[i * H + hh] = p;
                sum[hh] += p;
            }
        }
        #pragma unroll
        for (int off = 32; off; off >>= 1)
            #pragma unroll
            for (int hh = 0; hh < H; hh++) sum[hh] += __shfl_xor(sum[hh], off, 64);
        float inv[H];
        #pragma unroll
        for (int hh = 0; hh < H; hh++) inv[hh] = 1.f / (sum[hh] + 1e-16f);
        for (int i = lane; i < deg; i += 64)
            #pragma unroll
            for (int hh = 0; hh < H; hh++) s_a[i * H + hh] *= inv[hh];
    }
    __syncthreads();

    // all 256 threads: weighted gather over edges, dims tid and tid+256
    int d0 = tid, d1 = tid + 256;
    int h0 = d0 / C, h1 = d1 / C;
    float acc0 = 0.f, acc1 = 0.f;
    for (int i = 0; i < deg; i++) {
        const float* hr = h + (size_t)s_src[i] * HC;
        acc0 += s_a[i * H + h0] * hr[d0];
        acc1 += s_a[i * H + h1] * hr[d1];
    }
    float v0 = acc0 + bias[d0];
    float v1 = acc1 + bias[d1];
    v0 = v0 > 0.f ? v0 : 0.f;
    v1 = v1 > 0.f ? v1 : 0.f;
    size_t base = (size_t)node * HC;
    if (RES) { v0 += x[base + d0]; v1 += x[base + d1]; }
    x[base + d0] = v0;
    x[base + d1] = v1;
}

// ---------------- global mean pool per graph (batch is sorted) -------------
__global__ __launch_bounds__(256) void k_pool(const int* __restrict__ batch,
                                              const float* __restrict__ x,
                                              float* __restrict__ pooled) {
    int g = blockIdx.x;
    __shared__ int s_lo, s_hi;
    if (threadIdx.x == 0) {
        int lo = 0, hi = NN;
        while (lo < hi) { int mid = (lo + hi) >> 1; if (batch[mid] < g) lo = mid + 1; else hi = mid; }
        s_lo = lo;
        lo = 0; hi = NN;
        while (lo < hi) { int mid = (lo + hi) >> 1; if (batch[mid] < g + 1) lo = mid + 1; else hi = mid; }
        s_hi = lo;
    }
    __syncthreads();
    int lo = s_lo, hi = s_hi;
    float a0 = 0.f, a1 = 0.f;
    for (int n = lo; n < hi; n++) {
        a0 += x[(size_t)n * DD + threadIdx.x];
        a1 += x[(size_t)n * DD + threadIdx.x + 256];
    }
    float cnt = fmaxf((float)(hi - lo), 1.f);
    pooled[g * DD + threadIdx.x]       = a0 / cnt;
    pooled[g * DD + threadIdx.x + 256] = a1 / cnt;
}

// ---------------- MLP head layer: relu(bn(in @ W + b)) ---------------------
__global__ __launch_bounds__(256) void k_head_layer(const float* __restrict__ in,
                                                    const float* __restrict__ W,
                                                    const float* __restrict__ b,
                                                    const float* __restrict__ gam,
                                                    const float* __restrict__ bet,
                                                    const float* __restrict__ rm,
                                                    const float* __restrict__ rv,
                                                    float* __restrict__ out,
                                                    int Din, int Dout) {
    int idx = blockIdx.x * 256 + threadIdx.x;
    if (idx >= GG * Dout) return;
    int g = idx / Dout, j = idx % Dout;
    const float* row = in + (size_t)g * Din;
    float s = 0.f;
    for (int k = 0; k < Din; k++) s += row[k] * W[(size_t)k * Dout + j];
    s += b[j];
    s = (s - rm[j]) * rsqrtf(rv[j] + 1e-5f) * gam[j] + bet[j];
    out[idx] = s > 0.f ? s : 0.f;
}

__global__ __launch_bounds__(64) void k_head_final(const float* __restrict__ z,
                                                   const float* __restrict__ W3,
                                                   const float* __restrict__ b3,
                                                   float* __restrict__ out,
                                                   int Din) {
    int g = blockIdx.x, lane = threadIdx.x;
    float s = 0.f;
    for (int k = lane; k < Din; k += 64) s += z[(size_t)g * Din + k] * W3[k];
    #pragma unroll
    for (int off = 32; off; off >>= 1) s += __shfl_xor(s, off, 64);
    if (lane == 0) {
        s += b3[0];
        out[g] = 1.f / (1.f + __expf(-s));
    }
}

// ===========================================================================
extern "C" void kernel_launch(void* const* d_in, const int* in_sizes, int n_in,
                              void* d_out, int out_size, void* d_ws, size_t ws_size,
                              hipStream_t stream) {
    const int*   node_ids = (const int*)d_in[0];
    const int*   ei       = (const int*)d_in[1];
    const int*   batch    = (const int*)d_in[2];
    const float* emb      = (const float*)d_in[3];
    const float* W0  = (const float*)d_in[4],  *as0 = (const float*)d_in[5];
    const float* ad0 = (const float*)d_in[6],  *b0  = (const float*)d_in[7];
    const float* W1  = (const float*)d_in[8],  *as1 = (const float*)d_in[9];
    const float* ad1 = (const float*)d_in[10], *b1  = (const float*)d_in[11];
    const float* W2  = (const float*)d_in[12], *as2 = (const float*)d_in[13];
    const float* ad2 = (const float*)d_in[14], *b2  = (const float*)d_in[15];
    const float* dW1 = (const float*)d_in[16], *db1 = (const float*)d_in[17];
    const float* dg1 = (const float*)d_in[18], *dbt1= (const float*)d_in[19];
    const float* drm1= (const float*)d_in[20], *drv1= (const float*)d_in[21];
    const float* dW2 = (const float*)d_in[22], *db2 = (const float*)d_in[23];
    const float* dg2 = (const float*)d_in[24], *dbt2= (const float*)d_in[25];
    const float* drm2= (const float*)d_in[26], *drv2= (const float*)d_in[27];
    const float* dW3 = (const float*)d_in[28], *db3 = (const float*)d_in[29];
    const float* sW1 = (const float*)d_in[30], *sb1 = (const float*)d_in[31];
    const float* sg1 = (const float*)d_in[32], *sbt1= (const float*)d_in[33];
    const float* srm1= (const float*)d_in[34], *srv1= (const float*)d_in[35];
    const float* sW2 = (const float*)d_in[36], *sb2 = (const float*)d_in[37];
    const float* sg2 = (const float*)d_in[38], *sbt2= (const float*)d_in[39];
    const float* srm2= (const float*)d_in[40], *srv2= (const float*)d_in[41];
    const float* sW3 = (const float*)d_in[42], *sb3 = (const float*)d_in[43];

    const int* esrc = ei;
    const int* edst = ei + EE;

    // ---- workspace carve ----
    char* p = (char*)d_ws;
    auto alloc = [&](size_t bytes) { char* r = p; p += (bytes + 255) & ~(size_t)255; return (void*)r; };
    float* x       = (float*)alloc((size_t)NN * DD * 4);
    float* hbuf    = (float*)alloc((size_t)NN * DD * 4);
    float* es      = (float*)alloc((size_t)NN * 4 * 4);
    float* ed      = (float*)alloc((size_t)NN * 4 * 4);
    int*   deg     = (int*)alloc((size_t)NN * 4);
    int*   offsets = (int*)alloc((size_t)(NN + 1) * 4);
    int*   cursor  = (int*)alloc((size_t)NN * 4);
    int*   csr_src = (int*)alloc((size_t)ET * 4);
    float* pooled  = (float*)alloc((size_t)GG * DD * 4);
    float* z1      = (float*)alloc((size_t)GG * DD * 4);
    float* z2      = (float*)alloc((size_t)GG * 256 * 4);

    // ---- CSR build ----
    hipMemsetAsync(deg, 0, (size_t)NN * 4, stream);
    hipMemsetAsync(cursor, 0, (size_t)NN * 4, stream);
    k_count_deg<<<(ET + 255) / 256, 256, 0, stream>>>(edst, deg);
    k_scan<<<1, 1024, 0, stream>>>(deg, offsets);
    k_fill_csr<<<(ET + 255) / 256, 256, 0, stream>>>(esrc, edst, offsets, cursor, csr_src);

    // ---- x = emb[node_ids] ----
    k_gather_emb<<<(NN * 128 + 255) / 256, 256, 0, stream>>>(node_ids, (const float4*)emb, (float4*)x);

    dim3 ggrid(NN / 64, DD / 64);   // 625 x 8

    // ---- layer 0 (H=4, C=128, no residual) ----
    k_gemm<<<ggrid, 256, 0, stream>>>(x, W0, hbuf, NN, DD, DD);
    k_attn_scores<4, 128><<<(NN * 4 + 3) / 4, 256, 0, stream>>>(hbuf, as0, ad0, es, ed);
    k_gat_aggregate<4, 128, false><<<NN, 256, 0, stream>>>(hbuf, es, ed, offsets, csr_src, b0, x);

    // ---- layer 1 (H=4, C=128, +residual) ----
    k_gemm<<<ggrid, 256, 0, stream>>>(x, W1, hbuf, NN, DD, DD);
    k_attn_scores<4, 128><<<(NN * 4 + 3) / 4, 256, 0, stream>>>(hbuf, as1, ad1, es, ed);
    k_gat_aggregate<4, 128, true><<<NN, 256, 0, stream>>>(hbuf, es, ed, offsets, csr_src, b1, x);

    // ---- layer 2 (H=1, C=512, +residual) ----
    k_gemm<<<ggrid, 256, 0, stream>>>(x, W2, hbuf, NN, DD, DD);
    k_attn_scores<1, 512><<<(NN + 3) / 4, 256, 0, stream>>>(hbuf, as2, ad2, es, ed);
    k_gat_aggregate<1, 512, true><<<NN, 256, 0, stream>>>(hbuf, es, ed, offsets, csr_src, b2, x);

    // ---- pool ----
    k_pool<<<GG, 256, 0, stream>>>(batch, x, pooled);

    float* outp = (float*)d_out;
    // ---- danger head ----
    k_head_layer<<<(GG * 512 + 255) / 256, 256, 0, stream>>>(pooled, dW1, db1, dg1, dbt1, drm1, drv1, z1, 512, 512);
    k_head_layer<<<(GG * 256 + 255) / 256, 256, 0, stream>>>(z1, dW2, db2, dg2, dbt2, drm2, drv2, z2, 512, 256);
    k_head_final<<<GG, 64, 0, stream>>>(z2, dW3, db3, outp, 256);
    // ---- synergy head ----
    k_head_layer<<<(GG * 512 + 255) / 256, 256, 0, stream>>>(pooled, sW1, sb1, sg1, sbt1, srm1, srv1, z1, 512, 512);
    k_head_layer<<<(GG * 256 + 255) / 256, 256, 0, stream>>>(z1, sW2, sb2, sg2, sbt2, srm2, srv2, z2, 512, 256);
    k_head_final<<<GG, 64, 0, stream>>>(z2, sW3, sb3, outp + GG, 256);
}

// Round 3
// 1480.428 us; speedup vs baseline: 1.8582x; 1.8582x over previous
//
#include <hip/hip_runtime.h>
#include <hip/hip_bf16.h>
#include <stdint.h>

#define NN 40000     // nodes
#define EE 150000    // edges (before self loops)
#define ET 190000    // EE + NN
#define GG 128       // graphs
#define DD 512       // dim
#define MP 40064     // NN padded to 128 (GEMM M-tiles)
#define SCAN_B 157   // ceil(NN/256)

typedef __hip_bfloat16 bf16;
typedef __attribute__((ext_vector_type(8))) short s16x8;   // 8 bf16 (4 VGPRs)
typedef __attribute__((ext_vector_type(4))) float f32v4;

__device__ __forceinline__ float b2f(bf16 v) { return __bfloat162float(v); }
__device__ __forceinline__ bf16  f2b(float v) { return __float2bfloat16(v); }
__device__ __forceinline__ unsigned short f2bu(float v) {
    bf16 b = __float2bfloat16(v);
    return *(unsigned short*)&b;
}

// ---------------- embedding gather: x/xb[n] = emb[node_ids[n]] -------------
__global__ __launch_bounds__(256) void k_gather_emb(const int* __restrict__ ids,
                                                    const float4* __restrict__ emb4,
                                                    float4* __restrict__ x4,
                                                    bf16* __restrict__ xb) {
    int t = blockIdx.x * 256 + threadIdx.x;        // 128 float4 per row
    int n = t >> 7, c = t & 127;
    if (n >= NN) return;
    int id = ids[n];
    float4 v = emb4[(size_t)id * 128 + c];
    x4[(size_t)n * 128 + c] = v;
    ushort4 u;
    u.x = f2bu(v.x); u.y = f2bu(v.y); u.z = f2bu(v.z); u.w = f2bu(v.w);
    *(ushort4*)(xb + (size_t)n * DD + c * 4) = u;
}

// ---------------- weight transpose + bf16: Wt[n][k] = W[k][n] --------------
__global__ __launch_bounds__(256) void k_w2bf_t(const float* __restrict__ W,
                                                bf16* __restrict__ Wt) {
    int idx = blockIdx.x * 256 + threadIdx.x;      // n*512 + k
    if (idx >= DD * DD) return;
    int n = idx >> 9, k = idx & 511;
    Wt[idx] = f2b(W[(size_t)k * DD + n]);
}

// ---------------- bf16 MFMA GEMM: C(bf16) = A @ Bt^T -----------------------
// A [MP][512] bf16 row-major, Bt [512][512] bf16 (row n = column n of W).
// 128x128 tile, 256 thr = 4 waves (2x2), each wave 64x64 via 4x4 mfma 16x16x32.
__global__ __launch_bounds__(256) void k_gemm_mfma(const bf16* __restrict__ A,
                                                   const bf16* __restrict__ Bt,
                                                   bf16* __restrict__ C) {
    constexpr int K = DD, N = DD;
    __shared__ bf16 lA[128 * 32];
    __shared__ bf16 lB[128 * 32];
    int tid = threadIdx.x, lane = tid & 63, quad = lane >> 4, l16 = lane & 15;
    int w = tid >> 6;
    int m0 = blockIdx.x * 128, n0 = blockIdx.y * 128;
    int wm = (w & 1) * 64, wn = (w >> 1) * 64;

    // staging map: chunk = r*256 + tid (8 elems each); row = chunk>>2, c = chunk&3
    // xor swizzle: pos = (c + (row>>1)) & 3  (keeps frag reads 2-way max)
    int sdst[2]; const bf16 *pA[2], *pB[2];
    #pragma unroll
    for (int r = 0; r < 2; r++) {
        int chunk = r * 256 + tid;
        int row = chunk >> 2, c = chunk & 3;
        sdst[r] = row * 32 + (((c + (row >> 1)) & 3) * 8);
        pA[r] = A + (size_t)(m0 + row) * K + c * 8;
        pB[r] = Bt + (size_t)(n0 + row) * K + c * 8;
    }
    // fragment LDS element offsets (fixed across K-loop)
    int aoff[4], boff[4];
    #pragma unroll
    for (int i = 0; i < 4; i++) {
        int m = wm + i * 16 + l16;
        aoff[i] = m * 32 + (((quad + (m >> 1)) & 3) * 8);
        int n = wn + i * 16 + l16;
        boff[i] = n * 32 + (((quad + (n >> 1)) & 3) * 8);
    }

    f32v4 zero = 0;
    f32v4 acc[4][4];
    #pragma unroll
    for (int i = 0; i < 4; i++)
        #pragma unroll
        for (int j = 0; j < 4; j++) acc[i][j] = zero;

    for (int k0 = 0; k0 < K; k0 += 32) {
        __syncthreads();
        #pragma unroll
        for (int r = 0; r < 2; r++) {
            *(s16x8*)(lA + sdst[r]) = *(const s16x8*)(pA[r] + k0);
            *(s16x8*)(lB + sdst[r]) = *(const s16x8*)(pB[r] + k0);
        }
        __syncthreads();
        s16x8 a[4], b[4];
        #pragma unroll
        for (int i = 0; i < 4; i++) a[i] = *(const s16x8*)(lA + aoff[i]);
        #pragma unroll
        for (int j = 0; j < 4; j++) b[j] = *(const s16x8*)(lB + boff[j]);
        #pragma unroll
        for (int i = 0; i < 4; i++)
            #pragma unroll
            for (int j = 0; j < 4; j++)
                acc[i][j] = __builtin_amdgcn_mfma_f32_16x16x32_bf16(a[i], b[j], acc[i][j], 0, 0, 0);
    }

    // C/D layout: col = lane&15, row = quad*4 + reg   [m89/m91 verified]
    #pragma unroll
    for (int i = 0; i < 4; i++)
        #pragma unroll
        for (int j = 0; j < 4; j++) {
            int col = n0 + wn + j * 16 + l16;
            #pragma unroll
            for (int r = 0; r < 4; r++) {
                int row = m0 + wm + i * 16 + quad * 4 + r;
                C[(size_t)row * N + col] = f2b(acc[i][j][r]);
            }
        }
}

// ---------------- attention scores es/ed per (node, head) -----------------
template <int H, int C>
__global__ __launch_bounds__(256) void k_attn_scores(const bf16* __restrict__ h,
                                                     const float* __restrict__ a_s,
                                                     const float* __restrict__ a_d,
                                                     float* __restrict__ es,
                                                     float* __restrict__ ed) {
    int wave = threadIdx.x >> 6, lane = threadIdx.x & 63;
    int gw = blockIdx.x * 4 + wave;
    if (gw >= NN * H) return;
    int node = gw / H, head = gw % H;
    const bf16* hrow = h + (size_t)node * (H * C) + head * C;
    float ss = 0.f, sd = 0.f;
    for (int c = lane; c < C; c += 64) {
        float hv = b2f(hrow[c]);
        ss += hv * a_s[head * C + c];
        sd += hv * a_d[head * C + c];
    }
    #pragma unroll
    for (int off = 32; off; off >>= 1) {
        ss += __shfl_xor(ss, off, 64);
        sd += __shfl_xor(sd, off, 64);
    }
    if (lane == 0) { es[node * H + head] = ss; ed[node * H + head] = sd; }
}

// ---------------- CSR build ------------------------------------------------
__global__ __launch_bounds__(256) void k_count_deg(const int* __restrict__ edst,
                                                   int* __restrict__ deg) {
    int e = blockIdx.x * 256 + threadIdx.x;
    if (e >= ET) return;
    int dst = (e < EE) ? edst[e] : (e - EE);
    atomicAdd(&deg[dst], 1);
}

__global__ __launch_bounds__(256) void k_scan_local(const int* __restrict__ deg,
                                                    int* __restrict__ offs,
                                                    int* __restrict__ bsum) {
    __shared__ int buf[256];
    int i = blockIdx.x * 256 + threadIdx.x;
    int v = (i < NN) ? deg[i] : 0;
    buf[threadIdx.x] = v;
    __syncthreads();
    #pragma unroll
    for (int off = 1; off < 256; off <<= 1) {
        int t = (threadIdx.x >= (unsigned)off) ? buf[threadIdx.x - off] : 0;
        __syncthreads();
        buf[threadIdx.x] += t;
        __syncthreads();
    }
    if (i < NN) offs[i] = buf[threadIdx.x] - v;     // exclusive within block
    if (threadIdx.x == 255) bsum[blockIdx.x] = buf[255];
}

__global__ __launch_bounds__(256) void k_scan_bsums(const int* __restrict__ bsum,
                                                    int* __restrict__ boff) {
    __shared__ int buf[256];
    int v = (threadIdx.x < SCAN_B) ? bsum[threadIdx.x] : 0;
    buf[threadIdx.x] = v;
    __syncthreads();
    #pragma unroll
    for (int off = 1; off < 256; off <<= 1) {
        int t = (threadIdx.x >= (unsigned)off) ? buf[threadIdx.x - off] : 0;
        __syncthreads();
        buf[threadIdx.x] += t;
        __syncthreads();
    }
    if (threadIdx.x < SCAN_B) boff[threadIdx.x] = buf[threadIdx.x] - v;
}

__global__ __launch_bounds__(256) void k_scan_add(int* __restrict__ offs,
                                                  const int* __restrict__ boff) {
    int i = blockIdx.x * 256 + threadIdx.x;
    if (i < NN) offs[i] += boff[blockIdx.x];
    if (i == 0) offs[NN] = ET;
}

__global__ __launch_bounds__(256) void k_fill_csr(const int* __restrict__ esrc,
                                                  const int* __restrict__ edst,
                                                  const int* __restrict__ offsets,
                                                  int* __restrict__ cursor,
                                                  int* __restrict__ csr_src) {
    int e = blockIdx.x * 256 + threadIdx.x;
    if (e >= ET) return;
    int dst, src;
    if (e < EE) { dst = edst[e]; src = esrc[e]; }
    else        { dst = e - EE;  src = e - EE; }
    int slot = offsets[dst] + atomicAdd(&cursor[dst], 1);
    csr_src[slot] = src;
}

// ---------------- GAT softmax + aggregate + epilogue (per dst node) --------
// h bf16 [MP][H*C]; writes x (fp32) and xb (bf16 mirror for next GEMM).
template <int H, int C, bool RES>
__global__ __launch_bounds__(256) void k_gat_aggregate(const bf16* __restrict__ h,
                                                       const float* __restrict__ es,
                                                       const float* __restrict__ ed,
                                                       const int* __restrict__ offsets,
                                                       const int* __restrict__ csr_src,
                                                       const float* __restrict__ bias,
                                                       float* __restrict__ x,
                                                       bf16* __restrict__ xb) {
    constexpr int HC = H * C;
    __shared__ int   s_src[256];
    __shared__ float s_a[256 * H];
    int node = blockIdx.x;
    int beg = offsets[node];
    int deg = offsets[node + 1] - beg;
    if (deg > 256) deg = 256;   // not hit: max in-deg ~ 25
    int tid = threadIdx.x;

    if (tid < 64) {             // wave 0: per-head softmax, alpha -> LDS
        int lane = tid;
        float edl[H], m[H], sum[H];
        #pragma unroll
        for (int hh = 0; hh < H; hh++) { edl[hh] = ed[node * H + hh]; m[hh] = -1e30f; sum[hh] = 0.f; }
        for (int i = lane; i < deg; i += 64) {
            int src = csr_src[beg + i];
            s_src[i] = src;
            #pragma unroll
            for (int hh = 0; hh < H; hh++) {
                float e = es[src * H + hh] + edl[hh];
                e = e > 0.f ? e : 0.2f * e;     // leaky_relu 0.2
                s_a[i * H + hh] = e;
                m[hh] = fmaxf(m[hh], e);
            }
        }
        #pragma unroll
        for (int off = 32; off; off >>= 1)
            #pragma unroll
            for (int hh = 0; hh < H; hh++) m[hh] = fmaxf(m[hh], __shfl_xor(m[hh], off, 64));
        for (int i = lane; i < deg; i += 64) {
            #pragma unroll
            for (int hh = 0; hh < H; hh++) {
                float p = __expf(s_a[i * H + hh] - m[hh]);
                s_a[i * H + hh] = p;
                sum[hh] += p;
            }
        }
        #pragma unroll
        for (int off = 32; off; off >>= 1)
            #pragma unroll
            for (int hh = 0; hh < H; hh++) sum[hh] += __shfl_xor(sum[hh], off, 64);
        float inv[H];
        #pragma unroll
        for (int hh = 0; hh < H; hh++) inv[hh] = 1.f / (sum[hh] + 1e-16f);
        for (int i = lane; i < deg; i += 64)
            #pragma unroll
            for (int hh = 0; hh < H; hh++) s_a[i * H + hh] *= inv[hh];
    }
    __syncthreads();

    // 256 threads x 2 adjacent dims: one packed bf16x2 load per edge per thread
    int d0 = tid * 2;
    int hd = d0 / C;            // both dims in the same head (C even)
    float acc0 = 0.f, acc1 = 0.f;
    for (int i = 0; i < deg; i++) {
        unsigned u = *(const unsigned*)(h + (size_t)s_src[i] * HC + d0);
        float a = s_a[i * H + hd];
        acc0 += a * __uint_as_float(u << 16);
        acc1 += a * __uint_as_float(u & 0xffff0000u);
    }
    float v0 = acc0 + bias[d0];
    float v1 = acc1 + bias[d0 + 1];
    v0 = v0 > 0.f ? v0 : 0.f;
    v1 = v1 > 0.f ? v1 : 0.f;
    size_t base = (size_t)node * HC;
    if (RES) { v0 += x[base + d0]; v1 += x[base + d0 + 1]; }
    x[base + d0]     = v0;
    x[base + d0 + 1] = v1;
    unsigned ob = (unsigned)f2bu(v0) | ((unsigned)f2bu(v1) << 16);
    *(unsigned*)(xb + base + d0) = ob;
}

// ---------------- global mean pool per graph (batch is sorted) -------------
__global__ __launch_bounds__(256) void k_pool(const int* __restrict__ batch,
                                              const float* __restrict__ x,
                                              float* __restrict__ pooled) {
    int g = blockIdx.x;
    int d = blockIdx.y * 256 + threadIdx.x;
    __shared__ int s_lo, s_hi;
    if (threadIdx.x == 0) {
        int lo = 0, hi = NN;
        while (lo < hi) { int mid = (lo + hi) >> 1; if (batch[mid] < g) lo = mid + 1; else hi = mid; }
        s_lo = lo;
        lo = 0; hi = NN;
        while (lo < hi) { int mid = (lo + hi) >> 1; if (batch[mid] < g + 1) lo = mid + 1; else hi = mid; }
        s_hi = lo;
    }
    __syncthreads();
    int lo = s_lo, hi = s_hi;
    float a0 = 0.f;
    for (int n = lo; n < hi; n++) a0 += x[(size_t)n * DD + d];
    float cnt = fmaxf((float)(hi - lo), 1.f);
    pooled[g * DD + d] = a0 / cnt;
}

// ---------------- MLP head layer: relu(bn(in @ W + b)) ---------------------
__global__ __launch_bounds__(256) void k_head_layer(const float* __restrict__ in,
                                                    const float* __restrict__ W,
                                                    const float* __restrict__ b,
                                                    const float* __restrict__ gam,
                                                    const float* __restrict__ bet,
                                                    const float* __restrict__ rm,
                                                    const float* __restrict__ rv,
                                                    float* __restrict__ out,
                                                    int Din, int Dout) {
    int idx = blockIdx.x * 256 + threadIdx.x;
    if (idx >= GG * Dout) return;
    int g = idx / Dout, j = idx % Dout;
    const float* row = in + (size_t)g * Din;
    float s = 0.f;
    for (int k = 0; k < Din; k++) s += row[k] * W[(size_t)k * Dout + j];
    s += b[j];
    s = (s - rm[j]) * rsqrtf(rv[j] + 1e-5f) * gam[j] + bet[j];
    out[idx] = s > 0.f ? s : 0.f;
}

__global__ __launch_bounds__(64) void k_head_final(const float* __restrict__ z,
                                                   const float* __restrict__ W3,
                                                   const float* __restrict__ b3,
                                                   float* __restrict__ out,
                                                   int Din) {
    int g = blockIdx.x, lane = threadIdx.x;
    float s = 0.f;
    for (int k = lane; k < Din; k += 64) s += z[(size_t)g * Din + k] * W3[k];
    #pragma unroll
    for (int off = 32; off; off >>= 1) s += __shfl_xor(s, off, 64);
    if (lane == 0) {
        s += b3[0];
        out[g] = 1.f / (1.f + __expf(-s));
    }
}

// ===========================================================================
extern "C" void kernel_launch(void* const* d_in, const int* in_sizes, int n_in,
                              void* d_out, int out_size, void* d_ws, size_t ws_size,
                              hipStream_t stream) {
    const int*   node_ids = (const int*)d_in[0];
    const int*   ei       = (const int*)d_in[1];
    const int*   batch    = (const int*)d_in[2];
    const float* emb      = (const float*)d_in[3];
    const float* W0  = (const float*)d_in[4],  *as0 = (const float*)d_in[5];
    const float* ad0 = (const float*)d_in[6],  *b0  = (const float*)d_in[7];
    const float* W1  = (const float*)d_in[8],  *as1 = (const float*)d_in[9];
    const float* ad1 = (const float*)d_in[10], *b1  = (const float*)d_in[11];
    const float* W2  = (const float*)d_in[12], *as2 = (const float*)d_in[13];
    const float* ad2 = (const float*)d_in[14], *b2  = (const float*)d_in[15];
    const float* dW1 = (const float*)d_in[16], *db1 = (const float*)d_in[17];
    const float* dg1 = (const float*)d_in[18], *dbt1= (const float*)d_in[19];
    const float* drm1= (const float*)d_in[20], *drv1= (const float*)d_in[21];
    const float* dW2 = (const float*)d_in[22], *db2 = (const float*)d_in[23];
    const float* dg2 = (const float*)d_in[24], *dbt2= (const float*)d_in[25];
    const float* drm2= (const float*)d_in[26], *drv2= (const float*)d_in[27];
    const float* dW3 = (const float*)d_in[28], *db3 = (const float*)d_in[29];
    const float* sW1 = (const float*)d_in[30], *sb1 = (const float*)d_in[31];
    const float* sg1 = (const float*)d_in[32], *sbt1= (const float*)d_in[33];
    const float* srm1= (const float*)d_in[34], *srv1= (const float*)d_in[35];
    const float* sW2 = (const float*)d_in[36], *sb2 = (const float*)d_in[37];
    const float* sg2 = (const float*)d_in[38], *sbt2= (const float*)d_in[39];
    const float* srm2= (const float*)d_in[40], *srv2= (const float*)d_in[41];
    const float* sW3 = (const float*)d_in[42], *sb3 = (const float*)d_in[43];

    const int* esrc = ei;
    const int* edst = ei + EE;

    // ---- workspace carve ----
    char* p = (char*)d_ws;
    auto alloc = [&](size_t bytes) { char* r = p; p += (bytes + 255) & ~(size_t)255; return (void*)r; };
    float* x       = (float*)alloc((size_t)NN * DD * 4);      // fp32 features
    bf16*  xb      = (bf16*)alloc((size_t)MP * DD * 2);       // bf16 mirror (GEMM A)
    bf16*  hbuf    = (bf16*)alloc((size_t)MP * DD * 2);       // GEMM output h
    bf16*  Wt0     = (bf16*)alloc((size_t)DD * DD * 2);
    bf16*  Wt1     = (bf16*)alloc((size_t)DD * DD * 2);
    bf16*  Wt2     = (bf16*)alloc((size_t)DD * DD * 2);
    float* es      = (float*)alloc((size_t)NN * 4 * 4);
    float* ed      = (float*)alloc((size_t)NN * 4 * 4);
    int*   deg     = (int*)alloc((size_t)NN * 4);
    int*   offsets = (int*)alloc((size_t)(NN + 1) * 4);
    int*   cursor  = (int*)alloc((size_t)NN * 4);
    int*   csr_src = (int*)alloc((size_t)ET * 4);
    int*   bsum    = (int*)alloc((size_t)256 * 4);
    int*   boff    = (int*)alloc((size_t)256 * 4);
    float* pooled  = (float*)alloc((size_t)GG * DD * 4);
    float* z1      = (float*)alloc((size_t)GG * DD * 4);
    float* z2      = (float*)alloc((size_t)GG * 256 * 4);

    // ---- CSR build ----
    hipMemsetAsync(deg, 0, (size_t)NN * 4, stream);
    hipMemsetAsync(cursor, 0, (size_t)NN * 4, stream);
    k_count_deg<<<(ET + 255) / 256, 256, 0, stream>>>(edst, deg);
    k_scan_local<<<SCAN_B, 256, 0, stream>>>(deg, offsets, bsum);
    k_scan_bsums<<<1, 256, 0, stream>>>(bsum, boff);
    k_scan_add<<<SCAN_B, 256, 0, stream>>>(offsets, boff);
    k_fill_csr<<<(ET + 255) / 256, 256, 0, stream>>>(esrc, edst, offsets, cursor, csr_src);

    // ---- weights -> bf16 transposed ----
    k_w2bf_t<<<(DD * DD + 255) / 256, 256, 0, stream>>>(W0, Wt0);
    k_w2bf_t<<<(DD * DD + 255) / 256, 256, 0, stream>>>(W1, Wt1);
    k_w2bf_t<<<(DD * DD + 255) / 256, 256, 0, stream>>>(W2, Wt2);

    // ---- x, xb = emb[node_ids] ----
    k_gather_emb<<<(NN * 128 + 255) / 256, 256, 0, stream>>>(node_ids, (const float4*)emb, (float4*)x, xb);

    dim3 ggrid(MP / 128, DD / 128);   // 313 x 4

    // ---- layer 0 (H=4, C=128, no residual) ----
    k_gemm_mfma<<<ggrid, 256, 0, stream>>>(xb, Wt0, hbuf);
    k_attn_scores<4, 128><<<(NN * 4 + 3) / 4, 256, 0, stream>>>(hbuf, as0, ad0, es, ed);
    k_gat_aggregate<4, 128, false><<<NN, 256, 0, stream>>>(hbuf, es, ed, offsets, csr_src, b0, x, xb);

    // ---- layer 1 (H=4, C=128, +residual) ----
    k_gemm_mfma<<<ggrid, 256, 0, stream>>>(xb, Wt1, hbuf);
    k_attn_scores<4, 128><<<(NN * 4 + 3) / 4, 256, 0, stream>>>(hbuf, as1, ad1, es, ed);
    k_gat_aggregate<4, 128, true><<<NN, 256, 0, stream>>>(hbuf, es, ed, offsets, csr_src, b1, x, xb);

    // ---- layer 2 (H=1, C=512, +residual) ----
    k_gemm_mfma<<<ggrid, 256, 0, stream>>>(xb, Wt2, hbuf);
    k_attn_scores<1, 512><<<(NN + 3) / 4, 256, 0, stream>>>(hbuf, as2, ad2, es, ed);
    k_gat_aggregate<1, 512, true><<<NN, 256, 0, stream>>>(hbuf, es, ed, offsets, csr_src, b2, x, xb);

    // ---- pool ----
    dim3 pgrid(GG, 2);
    k_pool<<<pgrid, 256, 0, stream>>>(batch, x, pooled);

    float* outp = (float*)d_out;
    // ---- danger head ----
    k_head_layer<<<(GG * 512 + 255) / 256, 256, 0, stream>>>(pooled, dW1, db1, dg1, dbt1, drm1, drv1, z1, 512, 512);
    k_head_layer<<<(GG * 256 + 255) / 256, 256, 0, stream>>>(z1, dW2, db2, dg2, dbt2, drm2, drv2, z2, 512, 256);
    k_head_final<<<GG, 64, 0, stream>>>(z2, dW3, db3, outp, 256);
    // ---- synergy head ----
    k_head_layer<<<(GG * 512 + 255) / 256, 256, 0, stream>>>(pooled, sW1, sb1, sg1, sbt1, srm1, srv1, z1, 512, 512);
    k_head_layer<<<(GG * 256 + 255) / 256, 256, 0, stream>>>(z1, sW2, sb2, sg2, sbt2, srm2, srv2, z2, 512, 256);
    k_head_final<<<GG, 64, 0, stream>>>(z2, sW3, sb3, outp + GG, 256);
}

// Round 4
// 796.465 us; speedup vs baseline: 3.4540x; 1.8587x over previous
//
#include <hip/hip_runtime.h>
#include <hip/hip_bf16.h>
#include <stdint.h>

#define NN 40000     // nodes
#define EE 150000    // edges (before self loops)
#define ET 190000    // EE + NN
#define GG 128       // graphs
#define DD 512       // dim
#define MP 40064     // NN padded to 128 (GEMM M-tiles)
#define SCAN_B 157   // ceil(NN/256)

typedef __hip_bfloat16 bf16;
typedef __attribute__((ext_vector_type(8))) short s16x8;   // 8 bf16 (4 VGPRs)
typedef __attribute__((ext_vector_type(4))) float f32v4;

__device__ __forceinline__ float b2f(bf16 v) { return __bfloat162float(v); }
__device__ __forceinline__ bf16  f2b(float v) { return __float2bfloat16(v); }
__device__ __forceinline__ unsigned short f2bu(float v) {
    bf16 b = __float2bfloat16(v);
    return *(unsigned short*)&b;
}

// ---------------- embedding gather: x/xb[n] = emb[node_ids[n]] -------------
__global__ __launch_bounds__(256) void k_gather_emb(const int* __restrict__ ids,
                                                    const float4* __restrict__ emb4,
                                                    float4* __restrict__ x4,
                                                    bf16* __restrict__ xb) {
    int t = blockIdx.x * 256 + threadIdx.x;        // 128 float4 per row
    int n = t >> 7, c = t & 127;
    if (n >= NN) return;
    int id = ids[n];
    float4 v = emb4[(size_t)id * 128 + c];
    x4[(size_t)n * 128 + c] = v;
    ushort4 u;
    u.x = f2bu(v.x); u.y = f2bu(v.y); u.z = f2bu(v.z); u.w = f2bu(v.w);
    *(ushort4*)(xb + (size_t)n * DD + c * 4) = u;
}

// ---------------- weight transpose + bf16: Wt[n][k] = W[k][n] --------------
__global__ __launch_bounds__(256) void k_w2bf_t(const float* __restrict__ W,
                                                bf16* __restrict__ Wt) {
    int idx = blockIdx.x * 256 + threadIdx.x;      // n*512 + k
    if (idx >= DD * DD) return;
    int n = idx >> 9, k = idx & 511;
    Wt[idx] = f2b(W[(size_t)k * DD + n]);
}

// ---------------- bf16 MFMA GEMM: C(bf16) = A @ Bt^T -----------------------
// A [MP][512] bf16 row-major, Bt [512][512] bf16 (row n = column n of W).
// 128x128 tile, 256 thr = 4 waves (2x2), each wave 64x64 via 4x4 mfma 16x16x32.
__global__ __launch_bounds__(256) void k_gemm_mfma(const bf16* __restrict__ A,
                                                   const bf16* __restrict__ Bt,
                                                   bf16* __restrict__ C) {
    constexpr int K = DD, N = DD;
    __shared__ bf16 lA[128 * 32];
    __shared__ bf16 lB[128 * 32];
    int tid = threadIdx.x, lane = tid & 63, quad = lane >> 4, l16 = lane & 15;
    int w = tid >> 6;
    int m0 = blockIdx.x * 128, n0 = blockIdx.y * 128;
    int wm = (w & 1) * 64, wn = (w >> 1) * 64;

    int sdst[2]; const bf16 *pA[2], *pB[2];
    #pragma unroll
    for (int r = 0; r < 2; r++) {
        int chunk = r * 256 + tid;
        int row = chunk >> 2, c = chunk & 3;
        sdst[r] = row * 32 + (((c + (row >> 1)) & 3) * 8);
        pA[r] = A + (size_t)(m0 + row) * K + c * 8;
        pB[r] = Bt + (size_t)(n0 + row) * K + c * 8;
    }
    int aoff[4], boff[4];
    #pragma unroll
    for (int i = 0; i < 4; i++) {
        int m = wm + i * 16 + l16;
        aoff[i] = m * 32 + (((quad + (m >> 1)) & 3) * 8);
        int n = wn + i * 16 + l16;
        boff[i] = n * 32 + (((quad + (n >> 1)) & 3) * 8);
    }

    f32v4 zero = 0;
    f32v4 acc[4][4];
    #pragma unroll
    for (int i = 0; i < 4; i++)
        #pragma unroll
        for (int j = 0; j < 4; j++) acc[i][j] = zero;

    for (int k0 = 0; k0 < K; k0 += 32) {
        __syncthreads();
        #pragma unroll
        for (int r = 0; r < 2; r++) {
            *(s16x8*)(lA + sdst[r]) = *(const s16x8*)(pA[r] + k0);
            *(s16x8*)(lB + sdst[r]) = *(const s16x8*)(pB[r] + k0);
        }
        __syncthreads();
        s16x8 a[4], b[4];
        #pragma unroll
        for (int i = 0; i < 4; i++) a[i] = *(const s16x8*)(lA + aoff[i]);
        #pragma unroll
        for (int j = 0; j < 4; j++) b[j] = *(const s16x8*)(lB + boff[j]);
        #pragma unroll
        for (int i = 0; i < 4; i++)
            #pragma unroll
            for (int j = 0; j < 4; j++)
                acc[i][j] = __builtin_amdgcn_mfma_f32_16x16x32_bf16(a[i], b[j], acc[i][j], 0, 0, 0);
    }

    // C/D layout: col = lane&15, row = quad*4 + reg   [m89/m91 verified]
    #pragma unroll
    for (int i = 0; i < 4; i++)
        #pragma unroll
        for (int j = 0; j < 4; j++) {
            int col = n0 + wn + j * 16 + l16;
            #pragma unroll
            for (int r = 0; r < 4; r++) {
                int row = m0 + wm + i * 16 + quad * 4 + r;
                C[(size_t)row * N + col] = f2b(acc[i][j][r]);
            }
        }
}

// ---------------- attention scores es/ed per (node, head) -----------------
template <int H, int C>
__global__ __launch_bounds__(256) void k_attn_scores(const bf16* __restrict__ h,
                                                     const float* __restrict__ a_s,
                                                     const float* __restrict__ a_d,
                                                     float* __restrict__ es,
                                                     float* __restrict__ ed) {
    int wave = threadIdx.x >> 6, lane = threadIdx.x & 63;
    int gw = blockIdx.x * 4 + wave;
    if (gw >= NN * H) return;
    int node = gw / H, head = gw % H;
    const bf16* hrow = h + (size_t)node * (H * C) + head * C;
    float ss = 0.f, sd = 0.f;
    for (int c = lane; c < C; c += 64) {
        float hv = b2f(hrow[c]);
        ss += hv * a_s[head * C + c];
        sd += hv * a_d[head * C + c];
    }
    #pragma unroll
    for (int off = 32; off; off >>= 1) {
        ss += __shfl_xor(ss, off, 64);
        sd += __shfl_xor(sd, off, 64);
    }
    if (lane == 0) { es[node * H + head] = ss; ed[node * H + head] = sd; }
}

// ---------------- CSR build ------------------------------------------------
__global__ __launch_bounds__(256) void k_count_deg(const int* __restrict__ edst,
                                                   int* __restrict__ deg) {
    int e = blockIdx.x * 256 + threadIdx.x;
    if (e >= ET) return;
    int dst = (e < EE) ? edst[e] : (e - EE);
    atomicAdd(&deg[dst], 1);
}

__global__ __launch_bounds__(256) void k_scan_local(const int* __restrict__ deg,
                                                    int* __restrict__ offs,
                                                    int* __restrict__ bsum) {
    __shared__ int buf[256];
    int i = blockIdx.x * 256 + threadIdx.x;
    int v = (i < NN) ? deg[i] : 0;
    buf[threadIdx.x] = v;
    __syncthreads();
    #pragma unroll
    for (int off = 1; off < 256; off <<= 1) {
        int t = (threadIdx.x >= (unsigned)off) ? buf[threadIdx.x - off] : 0;
        __syncthreads();
        buf[threadIdx.x] += t;
        __syncthreads();
    }
    if (i < NN) offs[i] = buf[threadIdx.x] - v;     // exclusive within block
    if (threadIdx.x == 255) bsum[blockIdx.x] = buf[255];
}

__global__ __launch_bounds__(256) void k_scan_bsums(const int* __restrict__ bsum,
                                                    int* __restrict__ boff) {
    __shared__ int buf[256];
    int v = (threadIdx.x < SCAN_B) ? bsum[threadIdx.x] : 0;
    buf[threadIdx.x] = v;
    __syncthreads();
    #pragma unroll
    for (int off = 1; off < 256; off <<= 1) {
        int t = (threadIdx.x >= (unsigned)off) ? buf[threadIdx.x - off] : 0;
        __syncthreads();
        buf[threadIdx.x] += t;
        __syncthreads();
    }
    if (threadIdx.x < SCAN_B) boff[threadIdx.x] = buf[threadIdx.x] - v;
}

__global__ __launch_bounds__(256) void k_scan_add(int* __restrict__ offs,
                                                  const int* __restrict__ boff) {
    int i = blockIdx.x * 256 + threadIdx.x;
    if (i < NN) offs[i] += boff[blockIdx.x];
    if (i == 0) offs[NN] = ET;
}

__global__ __launch_bounds__(256) void k_fill_csr(const int* __restrict__ esrc,
                                                  const int* __restrict__ edst,
                                                  const int* __restrict__ offsets,
                                                  int* __restrict__ cursor,
                                                  int* __restrict__ csr_src) {
    int e = blockIdx.x * 256 + threadIdx.x;
    if (e >= ET) return;
    int dst, src;
    if (e < EE) { dst = edst[e]; src = esrc[e]; }
    else        { dst = e - EE;  src = e - EE; }
    int slot = offsets[dst] + atomicAdd(&cursor[dst], 1);
    csr_src[slot] = src;
}

// ---------------- GAT softmax + aggregate + epilogue (per dst node) --------
template <int H, int C, bool RES>
__global__ __launch_bounds__(256) void k_gat_aggregate(const bf16* __restrict__ h,
                                                       const float* __restrict__ es,
                                                       const float* __restrict__ ed,
                                                       const int* __restrict__ offsets,
                                                       const int* __restrict__ csr_src,
                                                       const float* __restrict__ bias,
                                                       float* __restrict__ x,
                                                       bf16* __restrict__ xb) {
    constexpr int HC = H * C;
    __shared__ int   s_src[256];
    __shared__ float s_a[256 * H];
    int node = blockIdx.x;
    int beg = offsets[node];
    int deg = offsets[node + 1] - beg;
    if (deg > 256) deg = 256;   // not hit: max in-deg ~ 25
    int tid = threadIdx.x;

    if (tid < 64) {             // wave 0: per-head softmax, alpha -> LDS
        int lane = tid;
        float edl[H], m[H], sum[H];
        #pragma unroll
        for (int hh = 0; hh < H; hh++) { edl[hh] = ed[node * H + hh]; m[hh] = -1e30f; sum[hh] = 0.f; }
        for (int i = lane; i < deg; i += 64) {
            int src = csr_src[beg + i];
            s_src[i] = src;
            #pragma unroll
            for (int hh = 0; hh < H; hh++) {
                float e = es[src * H + hh] + edl[hh];
                e = e > 0.f ? e : 0.2f * e;     // leaky_relu 0.2
                s_a[i * H + hh] = e;
                m[hh] = fmaxf(m[hh], e);
            }
        }
        #pragma unroll
        for (int off = 32; off; off >>= 1)
            #pragma unroll
            for (int hh = 0; hh < H; hh++) m[hh] = fmaxf(m[hh], __shfl_xor(m[hh], off, 64));
        for (int i = lane; i < deg; i += 64) {
            #pragma unroll
            for (int hh = 0; hh < H; hh++) {
                float p = __expf(s_a[i * H + hh] - m[hh]);
                s_a[i * H + hh] = p;
                sum[hh] += p;
            }
        }
        #pragma unroll
        for (int off = 32; off; off >>= 1)
            #pragma unroll
            for (int hh = 0; hh < H; hh++) sum[hh] += __shfl_xor(sum[hh], off, 64);
        float inv[H];
        #pragma unroll
        for (int hh = 0; hh < H; hh++) inv[hh] = 1.f / (sum[hh] + 1e-16f);
        for (int i = lane; i < deg; i += 64)
            #pragma unroll
            for (int hh = 0; hh < H; hh++) s_a[i * H + hh] *= inv[hh];
    }
    __syncthreads();

    // 256 threads x 2 adjacent dims: one packed bf16x2 load per edge per thread
    int d0 = tid * 2;
    int hd = d0 / C;            // both dims in the same head (C even)
    float acc0 = 0.f, acc1 = 0.f;
    for (int i = 0; i < deg; i++) {
        unsigned u = *(const unsigned*)(h + (size_t)s_src[i] * HC + d0);
        float a = s_a[i * H + hd];
        acc0 += a * __uint_as_float(u << 16);
        acc1 += a * __uint_as_float(u & 0xffff0000u);
    }
    float v0 = acc0 + bias[d0];
    float v1 = acc1 + bias[d0 + 1];
    v0 = v0 > 0.f ? v0 : 0.f;
    v1 = v1 > 0.f ? v1 : 0.f;
    size_t base = (size_t)node * HC;
    if (RES) { v0 += x[base + d0]; v1 += x[base + d0 + 1]; }
    x[base + d0]     = v0;
    x[base + d0 + 1] = v1;
    unsigned ob = (unsigned)f2bu(v0) | ((unsigned)f2bu(v1) << 16);
    *(unsigned*)(xb + base + d0) = ob;
}

// ---------------- global mean pool per graph (batch is sorted) -------------
__global__ __launch_bounds__(256) void k_pool(const int* __restrict__ batch,
                                              const float* __restrict__ x,
                                              float* __restrict__ pooled) {
    int g = blockIdx.x;
    int d = blockIdx.y * 256 + threadIdx.x;
    __shared__ int s_lo, s_hi;
    if (threadIdx.x == 0) {
        int lo = 0, hi = NN;
        while (lo < hi) { int mid = (lo + hi) >> 1; if (batch[mid] < g) lo = mid + 1; else hi = mid; }
        s_lo = lo;
        lo = 0; hi = NN;
        while (lo < hi) { int mid = (lo + hi) >> 1; if (batch[mid] < g + 1) lo = mid + 1; else hi = mid; }
        s_hi = lo;
    }
    __syncthreads();
    int lo = s_lo, hi = s_hi;
    float a0 = 0.f;
    for (int n = lo; n < hi; n++) a0 += x[(size_t)n * DD + d];
    float cnt = fmaxf((float)(hi - lo), 1.f);
    pooled[g * DD + d] = a0 / cnt;
}

// ---------------- dual-head MLP layer: relu(bn(in @ W + b)) ----------------
// grid (Dout/64, GG, 2); block 256 = 64 j-lanes x 4 k-slices.
// z selects danger (0) / synergy (1) parameter set.
template <int Din, int Dout>
__global__ __launch_bounds__(256) void k_head_layer2(const float* __restrict__ inD,
                                                     const float* __restrict__ inS,
                                                     const float* __restrict__ Wd, const float* __restrict__ bd,
                                                     const float* __restrict__ gd, const float* __restrict__ btd,
                                                     const float* __restrict__ rmd, const float* __restrict__ rvd,
                                                     const float* __restrict__ Ws, const float* __restrict__ bs_,
                                                     const float* __restrict__ gs, const float* __restrict__ bts,
                                                     const float* __restrict__ rms, const float* __restrict__ rvs,
                                                     float* __restrict__ outD,
                                                     float* __restrict__ outS) {
    const float *in, *W, *b, *ga, *bt, *rm, *rv; float* out;
    if (blockIdx.z == 0) { in = inD; W = Wd; b = bd; ga = gd; bt = btd; rm = rmd; rv = rvd; out = outD; }
    else                 { in = inS; W = Ws; b = bs_; ga = gs; bt = bts; rm = rms; rv = rvs; out = outS; }
    int g = blockIdx.y;
    int tid = threadIdx.x;
    int j = blockIdx.x * 64 + (tid & 63);
    int ks = tid >> 6;                       // 0..3, k-slice of Din/4
    __shared__ float s_in[Din];
    __shared__ float s_red[256];
    for (int k = tid; k < Din; k += 256) s_in[k] = in[(size_t)g * Din + k];
    __syncthreads();
    constexpr int KS = Din / 4;
    const float* Wp = W + (size_t)ks * KS * Dout + j;
    float acc = 0.f;
    #pragma unroll 8
    for (int k = 0; k < KS; k++) acc += s_in[ks * KS + k] * Wp[(size_t)k * Dout];
    s_red[tid] = acc;
    __syncthreads();
    if (tid < 64) {
        float s = s_red[tid] + s_red[tid + 64] + s_red[tid + 128] + s_red[tid + 192];
        s += b[j];
        s = (s - rm[j]) * rsqrtf(rv[j] + 1e-5f) * ga[j] + bt[j];
        out[(size_t)g * Dout + j] = s > 0.f ? s : 0.f;
    }
}

// ---------------- dual final: sigmoid(z @ W3 + b3), grid (GG, 2) -----------
__global__ __launch_bounds__(64) void k_head_final2(const float* __restrict__ zD,
                                                    const float* __restrict__ zS,
                                                    const float* __restrict__ W3d, const float* __restrict__ b3d,
                                                    const float* __restrict__ W3s, const float* __restrict__ b3s,
                                                    float* __restrict__ out, int Din) {
    const float* z; const float* W3; const float* b3; float* o;
    if (blockIdx.y == 0) { z = zD; W3 = W3d; b3 = b3d; o = out; }
    else                 { z = zS; W3 = W3s; b3 = b3s; o = out + GG; }
    int g = blockIdx.x, lane = threadIdx.x;
    float s = 0.f;
    for (int k = lane; k < Din; k += 64) s += z[(size_t)g * Din + k] * W3[k];
    #pragma unroll
    for (int off = 32; off; off >>= 1) s += __shfl_xor(s, off, 64);
    if (lane == 0) {
        s += b3[0];
        o[g] = 1.f / (1.f + __expf(-s));
    }
}

// ===========================================================================
extern "C" void kernel_launch(void* const* d_in, const int* in_sizes, int n_in,
                              void* d_out, int out_size, void* d_ws, size_t ws_size,
                              hipStream_t stream) {
    const int*   node_ids = (const int*)d_in[0];
    const int*   ei       = (const int*)d_in[1];
    const int*   batch    = (const int*)d_in[2];
    const float* emb      = (const float*)d_in[3];
    const float* W0  = (const float*)d_in[4],  *as0 = (const float*)d_in[5];
    const float* ad0 = (const float*)d_in[6],  *b0  = (const float*)d_in[7];
    const float* W1  = (const float*)d_in[8],  *as1 = (const float*)d_in[9];
    const float* ad1 = (const float*)d_in[10], *b1  = (const float*)d_in[11];
    const float* W2  = (const float*)d_in[12], *as2 = (const float*)d_in[13];
    const float* ad2 = (const float*)d_in[14], *b2  = (const float*)d_in[15];
    const float* dW1 = (const float*)d_in[16], *db1 = (const float*)d_in[17];
    const float* dg1 = (const float*)d_in[18], *dbt1= (const float*)d_in[19];
    const float* drm1= (const float*)d_in[20], *drv1= (const float*)d_in[21];
    const float* dW2 = (const float*)d_in[22], *db2 = (const float*)d_in[23];
    const float* dg2 = (const float*)d_in[24], *dbt2= (const float*)d_in[25];
    const float* drm2= (const float*)d_in[26], *drv2= (const float*)d_in[27];
    const float* dW3 = (const float*)d_in[28], *db3 = (const float*)d_in[29];
    const float* sW1 = (const float*)d_in[30], *sb1 = (const float*)d_in[31];
    const float* sg1 = (const float*)d_in[32], *sbt1= (const float*)d_in[33];
    const float* srm1= (const float*)d_in[34], *srv1= (const float*)d_in[35];
    const float* sW2 = (const float*)d_in[36], *sb2 = (const float*)d_in[37];
    const float* sg2 = (const float*)d_in[38], *sbt2= (const float*)d_in[39];
    const float* srm2= (const float*)d_in[40], *srv2= (const float*)d_in[41];
    const float* sW3 = (const float*)d_in[42], *sb3 = (const float*)d_in[43];

    const int* esrc = ei;
    const int* edst = ei + EE;

    // ---- workspace carve ----
    char* p = (char*)d_ws;
    auto alloc = [&](size_t bytes) { char* r = p; p += (bytes + 255) & ~(size_t)255; return (void*)r; };
    float* x       = (float*)alloc((size_t)NN * DD * 4);      // fp32 features
    bf16*  xb      = (bf16*)alloc((size_t)MP * DD * 2);       // bf16 mirror (GEMM A)
    bf16*  hbuf    = (bf16*)alloc((size_t)MP * DD * 2);       // GEMM output h
    bf16*  Wt0     = (bf16*)alloc((size_t)DD * DD * 2);
    bf16*  Wt1     = (bf16*)alloc((size_t)DD * DD * 2);
    bf16*  Wt2     = (bf16*)alloc((size_t)DD * DD * 2);
    float* es      = (float*)alloc((size_t)NN * 4 * 4);
    float* ed      = (float*)alloc((size_t)NN * 4 * 4);
    int*   deg     = (int*)alloc((size_t)NN * 4);
    int*   offsets = (int*)alloc((size_t)(NN + 1) * 4);
    int*   cursor  = (int*)alloc((size_t)NN * 4);
    int*   csr_src = (int*)alloc((size_t)ET * 4);
    int*   bsum    = (int*)alloc((size_t)256 * 4);
    int*   boff    = (int*)alloc((size_t)256 * 4);
    float* pooled  = (float*)alloc((size_t)GG * DD * 4);
    float* z1d     = (float*)alloc((size_t)GG * DD * 4);
    float* z1s     = (float*)alloc((size_t)GG * DD * 4);
    float* z2d     = (float*)alloc((size_t)GG * 256 * 4);
    float* z2s     = (float*)alloc((size_t)GG * 256 * 4);

    // ---- CSR build ----
    hipMemsetAsync(deg, 0, (size_t)NN * 4, stream);
    hipMemsetAsync(cursor, 0, (size_t)NN * 4, stream);
    k_count_deg<<<(ET + 255) / 256, 256, 0, stream>>>(edst, deg);
    k_scan_local<<<SCAN_B, 256, 0, stream>>>(deg, offsets, bsum);
    k_scan_bsums<<<1, 256, 0, stream>>>(bsum, boff);
    k_scan_add<<<SCAN_B, 256, 0, stream>>>(offsets, boff);
    k_fill_csr<<<(ET + 255) / 256, 256, 0, stream>>>(esrc, edst, offsets, cursor, csr_src);

    // ---- weights -> bf16 transposed ----
    k_w2bf_t<<<(DD * DD + 255) / 256, 256, 0, stream>>>(W0, Wt0);
    k_w2bf_t<<<(DD * DD + 255) / 256, 256, 0, stream>>>(W1, Wt1);
    k_w2bf_t<<<(DD * DD + 255) / 256, 256, 0, stream>>>(W2, Wt2);

    // ---- x, xb = emb[node_ids] ----
    k_gather_emb<<<(NN * 128 + 255) / 256, 256, 0, stream>>>(node_ids, (const float4*)emb, (float4*)x, xb);

    dim3 ggrid(MP / 128, DD / 128);   // 313 x 4

    // ---- layer 0 (H=4, C=128, no residual) ----
    k_gemm_mfma<<<ggrid, 256, 0, stream>>>(xb, Wt0, hbuf);
    k_attn_scores<4, 128><<<(NN * 4 + 3) / 4, 256, 0, stream>>>(hbuf, as0, ad0, es, ed);
    k_gat_aggregate<4, 128, false><<<NN, 256, 0, stream>>>(hbuf, es, ed, offsets, csr_src, b0, x, xb);

    // ---- layer 1 (H=4, C=128, +residual) ----
    k_gemm_mfma<<<ggrid, 256, 0, stream>>>(xb, Wt1, hbuf);
    k_attn_scores<4, 128><<<(NN * 4 + 3) / 4, 256, 0, stream>>>(hbuf, as1, ad1, es, ed);
    k_gat_aggregate<4, 128, true><<<NN, 256, 0, stream>>>(hbuf, es, ed, offsets, csr_src, b1, x, xb);

    // ---- layer 2 (H=1, C=512, +residual) ----
    k_gemm_mfma<<<ggrid, 256, 0, stream>>>(xb, Wt2, hbuf);
    k_attn_scores<1, 512><<<(NN + 3) / 4, 256, 0, stream>>>(hbuf, as2, ad2, es, ed);
    k_gat_aggregate<1, 512, true><<<NN, 256, 0, stream>>>(hbuf, es, ed, offsets, csr_src, b2, x, xb);

    // ---- pool ----
    dim3 pgrid(GG, 2);
    k_pool<<<pgrid, 256, 0, stream>>>(batch, x, pooled);

    float* outp = (float*)d_out;
    // ---- both heads, fused dual-launch ----
    dim3 h1grid(DD / 64, GG, 2);          // 8 x 128 x 2
    k_head_layer2<DD, DD><<<h1grid, 256, 0, stream>>>(pooled, pooled,
        dW1, db1, dg1, dbt1, drm1, drv1,
        sW1, sb1, sg1, sbt1, srm1, srv1, z1d, z1s);
    dim3 h2grid(256 / 64, GG, 2);         // 4 x 128 x 2
    k_head_layer2<DD, 256><<<h2grid, 256, 0, stream>>>(z1d, z1s,
        dW2, db2, dg2, dbt2, drm2, drv2,
        sW2, sb2, sg2, sbt2, srm2, srv2, z2d, z2s);
    dim3 fgrid(GG, 2);
    k_head_final2<<<fgrid, 64, 0, stream>>>(z2d, z2s, dW3, db3, sW3, sb3, outp, 256);
}